// Round 12
// baseline (79.390 us; speedup 1.0000x reference)
//
#include <hip/hip_runtime.h>
#include <hip/hip_bf16.h>

#define B_ 4
#define S_ 4096
#define DIN 512
#define DOUT 64
#define QB 64
#define KVB 64
#define NCHUNK_TOT 288   // sum over qt of ceil((qt+1)/8)

typedef __attribute__((ext_vector_type(8))) short short8;
typedef __attribute__((ext_vector_type(4))) float f32x4;

static __device__ __forceinline__ float fast_exp2(float x) {
    return __builtin_amdgcn_exp2f(x);   // v_exp_f32 (2^x)
}

static __device__ __forceinline__ unsigned short f2bf(float x) {
    union { float f; unsigned u; } v; v.f = x;
    unsigned r = v.u + 0x7FFF + ((v.u >> 16) & 1);  // round-to-nearest-even
    return (unsigned short)(r >> 16);
}

static __device__ __forceinline__ unsigned bf2pack(float a, float b) {
    __hip_bfloat162 h = __float22bfloat162_rn({a, b});
    return *reinterpret_cast<unsigned*>(&h);
}

static __device__ __forceinline__ void gload_lds16(const void* g, void* l) {
    __builtin_amdgcn_global_load_lds(
        (const __attribute__((address_space(1))) void*)g,
        (__attribute__((address_space(3))) void*)l, 16, 0, 0);
}

// ---------------------------------------------------------------------------
// Kernel 0: W [512][64] fp32 -> Wt [64][512] bf16 (x3). LDS-tiled transpose.
// ---------------------------------------------------------------------------
__global__ __launch_bounds__(256) void wt_kernel(
    const float* __restrict__ Wq, const float* __restrict__ Wk,
    const float* __restrict__ Wv, unsigned short* __restrict__ wt)
{
    __shared__ float tile[64 * 65];
    int p = blockIdx.y;
    int k0 = blockIdx.x * 64;
    const float* w = (p == 0) ? Wq : ((p == 1) ? Wk : Wv);
    unsigned short* o = wt + (size_t)p * DIN * DOUT;
    int t = threadIdx.x;
    for (int i = 0; i < 16; ++i) {
        int flat = i * 256 + t;
        int ki = flat >> 6, di = flat & 63;
        tile[ki * 65 + di] = w[(size_t)(k0 + ki) * DOUT + di];
    }
    __syncthreads();
    for (int i = 0; i < 16; ++i) {
        int flat = i * 256 + t;
        int d = flat >> 6, k = flat & 63;
        o[(size_t)d * DIN + k0 + k] = f2bf(tile[k * 65 + d]);
    }
}

// ---------------------------------------------------------------------------
// Kernel 1a: PURE streaming convert fp32 -> bf16 (diagnostic + BW saver).
// Perfectly coalesced: 32 B loads / 16 B stores per lane, grid-stride,
// no LDS, no barriers. grid (1024, 3) = full occupancy.
// ---------------------------------------------------------------------------
__global__ __launch_bounds__(256) void conv_kernel(
    const float* __restrict__ q_in, const float* __restrict__ k_in,
    const float* __restrict__ v_in, unsigned short* __restrict__ abf)
{
    int p = blockIdx.y;
    const float* in = (p == 0) ? q_in : ((p == 1) ? k_in : v_in);
    unsigned short* o = abf + (size_t)p * B_ * S_ * DIN;
    size_t n8 = (size_t)B_ * S_ * DIN / 8;           // groups of 8 floats
    size_t stride = (size_t)gridDim.x * blockDim.x;
    for (size_t i = (size_t)blockIdx.x * blockDim.x + threadIdx.x; i < n8; i += stride) {
        const float4* src = reinterpret_cast<const float4*>(in + i * 8);
        float4 x0 = src[0], x1 = src[1];
        short8 v;
        unsigned* u = reinterpret_cast<unsigned*>(&v);
        u[0] = bf2pack(x0.x, x0.y); u[1] = bf2pack(x0.z, x0.w);
        u[2] = bf2pack(x1.x, x1.y); u[3] = bf2pack(x1.z, x1.w);
        *reinterpret_cast<short8*>(o + i * 8) = v;
    }
}

// ---------------------------------------------------------------------------
// Kernel 1b: projections from bf16 A (half the bytes, zero in-loop cvt).
// Chunked K pipeline (chunk = 64 cols): A-chunk 8 KB + B-chunk 8 KB staged
// via global_load_lds into double-buffered swizzled LDS (32 KB total ->
// up to 5 blocks/CU). A and B have identical 1-KB row strides (symmetric).
// grid (256, 3) x 256 thr (4 waves x 16 rows).
// ---------------------------------------------------------------------------
__global__ __launch_bounds__(256) void gemm_kernel(
    const unsigned short* __restrict__ abf, const unsigned short* __restrict__ wt,
    unsigned short* __restrict__ qb, unsigned short* __restrict__ kb,
    unsigned short* __restrict__ vtb)
{
    __shared__ unsigned short a_lds[2][64 * 64];   // 2 x 8 KB bf16
    __shared__ unsigned short b_lds[2][64 * 64];   // 2 x 8 KB bf16
    int p = blockIdx.y;
    const char* a_g = (const char*)(abf + (size_t)p * B_ * S_ * DIN
                                        + (size_t)blockIdx.x * 64 * DIN);  // row stride 1 KB
    const char* w_g = (const char*)(wt + (size_t)p * DIN * DOUT);           // row stride 1 KB
    int tid = threadIdx.x, wv = tid >> 6, lane = tid & 63;
    int lrow = lane & 15, lkhi = lane >> 4;
    int m0w = blockIdx.x * 64 + wv * 16;

    // stage one chunk: 8 rows x 128 B per gload (1 KB), 2 gloads each for A,B
#define PSTAGE(buf, kc_) do {                                                   \
    _Pragma("unroll")                                                           \
    for (int h = 0; h < 2; ++h) {                                               \
        int drow = h * 32 + wv * 8 + (lane >> 3);                               \
        int offg = ((lane & 7) * 16) ^ ((drow & 7) << 4);                       \
        gload_lds16(a_g + (size_t)drow * 1024 + (kc_) * 128 + offg,             \
                    (char*)a_lds[buf] + h * 4096 + wv * 1024);                  \
        gload_lds16(w_g + (size_t)drow * 1024 + (kc_) * 128 + offg,             \
                    (char*)b_lds[buf] + h * 4096 + wv * 1024);                  \
    }                                                                           \
} while (0)

    PSTAGE(0, 0);
    asm volatile("s_waitcnt vmcnt(0)" ::: "memory");
    __builtin_amdgcn_s_barrier();
    asm volatile("" ::: "memory");

    f32x4 acc[4] = {};
    int row_a = wv * 16 + lrow;
    int axor = (row_a & 7) << 4;
    int cur = 0;

#pragma unroll
    for (int kc = 0; kc < 8; ++kc) {
        if (kc < 7) {
            PSTAGE(cur ^ 1, kc + 1);                        // prefetch next chunk
            asm volatile("s_waitcnt vmcnt(4)" ::: "memory");  // current chunk landed
        } else {
            asm volatile("s_waitcnt vmcnt(0)" ::: "memory");
        }
        __builtin_amdgcn_s_barrier();
        asm volatile("" ::: "memory");

        const char* abuf = (const char*)a_lds[cur];
        const char* bbuf = (const char*)b_lds[cur];
#pragma unroll
        for (int kk = 0; kk < 2; ++kk) {
            int aoff = row_a * 128 + ((kk * 64 + lkhi * 16) ^ axor);
            short8 af = *reinterpret_cast<const short8*>(abuf + aoff);
#pragma unroll
            for (int ct = 0; ct < 4; ++ct) {
                int row_b = ct * 16 + lrow;
                int boff = row_b * 128 + ((kk * 64 + lkhi * 16) ^ ((row_b & 7) << 4));
                short8 bf = *reinterpret_cast<const short8*>(bbuf + boff);
                acc[ct] = __builtin_amdgcn_mfma_f32_16x16x32_bf16(af, bf, acc[ct], 0, 0, 0);
            }
        }
        __builtin_amdgcn_s_barrier();   // readers done before buf is restaged
        asm volatile("" ::: "memory");
        cur ^= 1;
    }
#undef PSTAGE

    // ---- epilogue ----
    float scale = (p == 0) ? 0.18033688011112042f : 1.0f;  // 0.125*log2(e)
    for (int ct = 0; ct < 4; ++ct) {
        for (int r = 0; r < 4; ++r) {
            int row = m0w + lkhi * 4 + r;       // global flat s index
            int col = ct * 16 + lrow;           // output dim
            unsigned short val = f2bf(acc[ct][r] * scale);
            if (p == 0)       qb[(size_t)row * DOUT + col] = val;
            else if (p == 1)  kb[(size_t)row * DOUT + col] = val;
            else {
                int bb = row >> 12, ss = row & 4095;
                vtb[((size_t)bb * DOUT + col) * S_ + ss] = val;
            }
        }
    }
}

// ---------------------------------------------------------------------------
// Kernel 2a: split-KV causal flash attention, phase 1 (partials).
// Swapped QK^T: sc = mfma(K, Q) -> lane holds S[q=qloc][kv=ct*16+lkhi4+r].
// Row-softmax = in-lane trees + 2 shuffles. Log2 domain.
// ---------------------------------------------------------------------------
__global__ __launch_bounds__(256) void attn_part(
    const unsigned short* __restrict__ qb, const unsigned short* __restrict__ kb,
    const unsigned short* __restrict__ vtb, float* __restrict__ Opart,
    float* __restrict__ ml)
{
    __shared__ unsigned short k_lds[2][KVB * DOUT];   // 2 x 8 KB
    __shared__ unsigned short v_lds[2][DOUT * KVB];   // 2 x 8 KB
    __shared__ unsigned short p_lds[4][16 * KVB];     // 8 KB

    int b = blockIdx.y;
    int x = NCHUNK_TOT - 1 - blockIdx.x;   // longest-first dispatch order
    int m = 0;
    while (4 * (m + 1) * (m + 2) <= x) ++m;
    int rem = x - 4 * m * (m + 1);
    int j = rem / (m + 1), c = rem % (m + 1);
    int qt = 8 * m + j;

    int q0 = qt * QB;
    int tid = threadIdx.x, wv = tid >> 6, lane = tid & 63;
    int lrow = lane & 15, lkhi = lane >> 4;
    int lkhi4 = lkhi * 4;
    int qloc = wv * 16 + lrow;             // q-row (block-local) this lane reduces

    const unsigned short* Qbase = qb + ((size_t)b * S_ + q0 + wv * 16 + lrow) * DOUT;
    short8 qf[2];
    qf[0] = *reinterpret_cast<const short8*>(Qbase + lkhi * 8);
    qf[1] = *reinterpret_cast<const short8*>(Qbase + 32 + lkhi * 8);

    f32x4 o[4] = {};
    float m_run = -INFINITY, l_run = 0.f;   // stats for q = qloc (log2 domain)

    const unsigned short* Kg = kb + (size_t)b * S_ * DOUT;
    const unsigned short* Vg = vtb + (size_t)b * DOUT * S_;
    char* pw = reinterpret_cast<char*>(p_lds[wv]);

    int srow_lo = (lane >> 3);             // 0..7
    int schunk = (lane & 7) * 16;          // within-row byte
    int soff = schunk ^ (srow_lo << 4);    // inverse-swizzled source byte

    int kv_beg = c * 8;
    int kv_end = min(kv_beg + 8, qt + 1);
    int cur = 0;

#define STAGE(buf, kvt_) do {                                                  \
    int kv0_ = (kvt_) * KVB;                                                   \
    for (int h = 0; h < 2; ++h) {                                              \
        int r_ = wv * 16 + h * 8 + srow_lo;                                    \
        const char* gk_ = (const char*)(Kg + (size_t)(kv0_ + r_) * DOUT) + soff; \
        gload_lds16(gk_, (char*)k_lds[buf] + wv * 2048 + h * 1024);            \
        const char* gv_ = (const char*)(Vg + (size_t)r_ * S_ + kv0_) + soff;   \
        gload_lds16(gv_, (char*)v_lds[buf] + wv * 2048 + h * 1024);            \
    }                                                                          \
} while (0)

    STAGE(0, kv_beg);
    asm volatile("s_waitcnt vmcnt(0)" ::: "memory");
    __builtin_amdgcn_s_barrier();
    asm volatile("" ::: "memory");

    for (int kvt = kv_beg; kvt < kv_end; ++kvt) {
        if (kvt + 1 < kv_end) STAGE(cur ^ 1, kvt + 1);  // prefetch under compute

        const char* kl = (const char*)k_lds[cur];
        const char* vl = (const char*)v_lds[cur];

        // swapped QK^T: sc[ct][r] = S[q=qloc][kv = ct*16+lkhi4+r]
        f32x4 sc[4];
        __builtin_amdgcn_s_setprio(1);
        for (int ct = 0; ct < 4; ++ct) {
            f32x4 a = {};
            for (int ds = 0; ds < 2; ++ds) {
                int r = ct * 16 + lrow;
                int byte = (r * 128 + (ds * 32 + lkhi * 8) * 2) ^ ((r & 7) << 4);
                short8 kf = *reinterpret_cast<const short8*>(kl + byte);
                a = __builtin_amdgcn_mfma_f32_16x16x32_bf16(kf, qf[ds], a, 0, 0, 0);
            }
            sc[ct] = a;
        }
        __builtin_amdgcn_s_setprio(0);

        // causal mask (diag tile only): kv_local > q_local (incl. wave offset!)
        if (kvt == qt) {
            for (int ct = 0; ct < 4; ++ct)
                for (int r = 0; r < 4; ++r)
                    if (ct * 16 + lkhi4 + r > qloc) sc[ct][r] = -INFINITY;
        }

        // row max: in-lane tree + xor16/xor32
        float mx4[4];
        for (int ct = 0; ct < 4; ++ct)
            mx4[ct] = fmaxf(fmaxf(sc[ct][0], sc[ct][1]), fmaxf(sc[ct][2], sc[ct][3]));
        float mxl = fmaxf(fmaxf(mx4[0], mx4[1]), fmaxf(mx4[2], mx4[3]));
        mxl = fmaxf(mxl, __shfl_xor(mxl, 16));
        mxl = fmaxf(mxl, __shfl_xor(mxl, 32));
        float mnew = fmaxf(m_run, mxl);
        float corr = fast_exp2(m_run - mnew);

        // P = exp2(S - mnew); row sum
        float s4[4];
        for (int ct = 0; ct < 4; ++ct) {
            sc[ct][0] = fast_exp2(sc[ct][0] - mnew);
            sc[ct][1] = fast_exp2(sc[ct][1] - mnew);
            sc[ct][2] = fast_exp2(sc[ct][2] - mnew);
            sc[ct][3] = fast_exp2(sc[ct][3] - mnew);
            s4[ct] = (sc[ct][0] + sc[ct][1]) + (sc[ct][2] + sc[ct][3]);
        }
        float rs = (s4[0] + s4[1]) + (s4[2] + s4[3]);
        rs += __shfl_xor(rs, 16);
        rs += __shfl_xor(rs, 32);
        l_run = l_run * corr + rs;
        m_run = mnew;

        // rescale O (o[ct2][r] is row q=lkhi4+r; corr lives in lane lkhi4+r)
        float corrq[4];
        for (int r = 0; r < 4; ++r) corrq[r] = __shfl(corr, lkhi4 + r);
        for (int ct2 = 0; ct2 < 4; ++ct2)
            for (int r = 0; r < 4; ++r)
                o[ct2][r] *= corrq[r];

        // P -> per-wave LDS (A-layout source): row=q=lrow, col=kv, b64 packed
        for (int ct = 0; ct < 4; ++ct) {
            uint2 pk;
            pk.x = bf2pack(sc[ct][0], sc[ct][1]);
            pk.y = bf2pack(sc[ct][2], sc[ct][3]);
            int byte = (lrow * 128 + (ct * 16 + lkhi4) * 2) ^ ((lrow & 7) << 4);
            *reinterpret_cast<uint2*>(pw + byte) = pk;
        }

        // PV: A = P (rows=q), B = Vt (cols=d, k=kv contiguous)
        __builtin_amdgcn_s_setprio(1);
        for (int ct2 = 0; ct2 < 4; ++ct2) {
            for (int ks = 0; ks < 2; ++ks) {
                int pbyte = (lrow * 128 + (ks * 32 + lkhi * 8) * 2) ^ ((lrow & 7) << 4);
                short8 pf = *reinterpret_cast<const short8*>(pw + pbyte);
                int vr = ct2 * 16 + lrow;
                int vbyte = (vr * 128 + (ks * 32 + lkhi * 8) * 2) ^ ((vr & 7) << 4);
                short8 vf = *reinterpret_cast<const short8*>(vl + vbyte);
                o[ct2] = __builtin_amdgcn_mfma_f32_16x16x32_bf16(pf, vf, o[ct2], 0, 0, 0);
            }
        }
        __builtin_amdgcn_s_setprio(0);
        __syncthreads();   // drains the prefetch issued at loop top
        cur ^= 1;
    }
#undef STAGE

    // write partials (unnormalized O + per-row m,l in log2 domain)
    float* Op = Opart + ((size_t)b * NCHUNK_TOT + x) * (64 * 64);
    float* Ml = ml + ((size_t)b * NCHUNK_TOT + x) * (64 * 2);
    for (int r = 0; r < 4; ++r) {
        int qr = wv * 16 + lkhi4 + r;
        for (int ct2 = 0; ct2 < 4; ++ct2)
            Op[qr * 64 + ct2 * 16 + lrow] = o[ct2][r];
    }
    if (lkhi == 0) {
        int qr = wv * 16 + lrow;
        Ml[qr * 2 + 0] = m_run;
        Ml[qr * 2 + 1] = l_run;
    }
}

// ---------------------------------------------------------------------------
// Kernel 2b: combine partials (log2-domain m). grid (64 qtiles, B), 256 thr.
// ---------------------------------------------------------------------------
__global__ __launch_bounds__(256) void attn_combine(
    const float* __restrict__ Opart, const float* __restrict__ ml,
    float* __restrict__ out)
{
    int qt = blockIdx.x, b = blockIdx.y;
    int m = qt >> 3;
    int nch = m + 1;
    int cbase = 4 * m * (m + 1) + (qt - 8 * m) * nch;

    int r = threadIdx.x >> 2;
    int cg = (threadIdx.x & 3) * 16;

    float M = -INFINITY;
    for (int c = 0; c < nch; ++c)
        M = fmaxf(M, ml[(((size_t)b * NCHUNK_TOT + cbase + c) * 64 + r) * 2]);

    float L = 0.f;
    f32x4 acc[4] = {};
    for (int c = 0; c < nch; ++c) {
        size_t ci = (size_t)b * NCHUNK_TOT + cbase + c;
        float mc = ml[(ci * 64 + r) * 2 + 0];
        float lc = ml[(ci * 64 + r) * 2 + 1];
        float w = fast_exp2(mc - M);
        L += lc * w;
        const f32x4* Op = reinterpret_cast<const f32x4*>(Opart + ci * (64 * 64) + r * 64 + cg);
        for (int i = 0; i < 4; ++i) {
            f32x4 v = Op[i];
            acc[i] += v * w;
        }
    }
    float inv = 1.f / L;
    f32x4* dst = reinterpret_cast<f32x4*>(out + (((size_t)b * S_) + qt * 64 + r) * DOUT + cg);
    for (int i = 0; i < 4; ++i)
        dst[i] = acc[i] * inv;
}

extern "C" void kernel_launch(void* const* d_in, const int* in_sizes, int n_in,
                              void* d_out, int out_size, void* d_ws, size_t ws_size,
                              hipStream_t stream) {
    const float* key_in = (const float*)d_in[0];
    const float* val_in = (const float*)d_in[1];
    const float* qry_in = (const float*)d_in[2];
    const float* Wk = (const float*)d_in[3];
    const float* Wv = (const float*)d_in[4];
    const float* Wq = (const float*)d_in[5];
    float* out = (float*)d_out;

    char* ws = (char*)d_ws;
    size_t off = 0;
    unsigned short* qb  = (unsigned short*)(ws + off); off += (size_t)B_ * S_ * DOUT * 2;
    unsigned short* kb  = (unsigned short*)(ws + off); off += (size_t)B_ * S_ * DOUT * 2;
    unsigned short* vtb = (unsigned short*)(ws + off); off += (size_t)B_ * S_ * DOUT * 2;
    unsigned short* wt  = (unsigned short*)(ws + off); off += (size_t)3 * DIN * DOUT * 2;
    float* Opart = (float*)(ws + off); off += (size_t)B_ * NCHUNK_TOT * 64 * 64 * 4;
    float* ml    = (float*)(ws + off); off += (size_t)B_ * NCHUNK_TOT * 64 * 2 * 4;
    // abf (50.3 MB) aliases Opart (75.5 MB): abf is dead before attn_part writes.
    unsigned short* abf = (unsigned short*)Opart;

    wt_kernel<<<dim3(8, 3), 256, 0, stream>>>(Wq, Wk, Wv, wt);
    conv_kernel<<<dim3(1024, 3), 256, 0, stream>>>(qry_in, key_in, val_in, abf);
    gemm_kernel<<<dim3(256, 3), 256, 0, stream>>>(abf, wt, qb, kb, vtb);
    attn_part<<<dim3(NCHUNK_TOT, B_), 256, 0, stream>>>(qb, kb, vtb, Opart, ml);
    attn_combine<<<dim3(S_ / QB, B_), 256, 0, stream>>>(Opart, ml, out);
}

// Round 13
// 62.958 us; speedup vs baseline: 1.2610x; 1.2610x over previous
//
#include <hip/hip_runtime.h>
#include <hip/hip_bf16.h>

#define B_ 4
#define S_ 4096
#define DIN 512
#define DOUT 64
#define QB 64
#define KVB 64
#define NCHUNK_TOT 288   // sum over qt of ceil((qt+1)/8)

typedef __attribute__((ext_vector_type(8))) short short8;
typedef __attribute__((ext_vector_type(4))) float f32x4;

static __device__ __forceinline__ float fast_exp2(float x) {
    return __builtin_amdgcn_exp2f(x);   // v_exp_f32 (2^x)
}

static __device__ __forceinline__ unsigned short f2bf(float x) {
    union { float f; unsigned u; } v; v.f = x;
    unsigned r = v.u + 0x7FFF + ((v.u >> 16) & 1);  // round-to-nearest-even
    return (unsigned short)(r >> 16);
}

static __device__ __forceinline__ float bf2f(unsigned short u) {
    union { unsigned u; float f; } v; v.u = ((unsigned)u) << 16; return v.f;
}

static __device__ __forceinline__ unsigned bf2pack(float a, float b) {
    __hip_bfloat162 h = __float22bfloat162_rn({a, b});
    return *reinterpret_cast<unsigned*>(&h);
}

static __device__ __forceinline__ void gload_lds16(const void* g, void* l) {
    __builtin_amdgcn_global_load_lds(
        (const __attribute__((address_space(1))) void*)g,
        (__attribute__((address_space(3))) void*)l, 16, 0, 0);
}

// ---------------------------------------------------------------------------
// Kernel 0: W [512][64] fp32 -> Wt [64][512] bf16 (x3). LDS-tiled transpose.
// ---------------------------------------------------------------------------
__global__ __launch_bounds__(256) void wt_kernel(
    const float* __restrict__ Wq, const float* __restrict__ Wk,
    const float* __restrict__ Wv, unsigned short* __restrict__ wt)
{
    __shared__ float tile[64 * 65];
    int p = blockIdx.y;
    int k0 = blockIdx.x * 64;
    const float* w = (p == 0) ? Wq : ((p == 1) ? Wk : Wv);
    unsigned short* o = wt + (size_t)p * DIN * DOUT;
    int t = threadIdx.x;
    for (int i = 0; i < 16; ++i) {
        int flat = i * 256 + t;
        int ki = flat >> 6, di = flat & 63;
        tile[ki * 65 + di] = w[(size_t)(k0 + ki) * DOUT + di];
    }
    __syncthreads();
    for (int i = 0; i < 16; ++i) {
        int flat = i * 256 + t;
        int d = flat >> 6, k = flat & 63;
        o[(size_t)d * DIN + k0 + k] = f2bf(tile[k * 65 + d]);
    }
}

// ---------------------------------------------------------------------------
// Kernel 1: projections, 8-deep K-chunk pipeline (R11 structure, best known).
// Per chunk: global_load_lds stages A (fp32 16KB) + B (Wt bf16 8KB) into
// double-buffered swizzled LDS; counted vmcnt(6) keeps next chunk's loads
// in flight across the barrier. grid (256, 3) x 256 thr. 48 KB -> 3 blk/CU.
// ---------------------------------------------------------------------------
__global__ __launch_bounds__(256) void proj_kernel(
    const float* __restrict__ q_in, const float* __restrict__ k_in,
    const float* __restrict__ v_in, const unsigned short* __restrict__ wt,
    unsigned short* __restrict__ qb, unsigned short* __restrict__ kb,
    unsigned short* __restrict__ vtb)
{
    __shared__ float a_lds[2][64 * 64];            // 2 x 16 KB fp32
    __shared__ unsigned short b_lds[2][64 * 64];   // 2 x 8 KB bf16
    int p = blockIdx.y;
    const float* in = (p == 0) ? q_in : ((p == 1) ? k_in : v_in);
    const unsigned short* w = wt + (size_t)p * DIN * DOUT;
    int tid = threadIdx.x, wv = tid >> 6, lane = tid & 63;
    int lrow = lane & 15, lkhi = lane >> 4;
    int m0 = blockIdx.x * 64;
    int m0w = m0 + wv * 16;

    const char* in_b = (const char*)(in + (size_t)m0 * DIN);   // row stride 2048 B
    const char* w_b  = (const char*)w;                          // row stride 1024 B

#define PSTAGE(buf, kc_) do {                                                   \
    _Pragma("unroll")                                                           \
    for (int i = 0; i < 4; ++i) {       /* A: 16 KB */                          \
        int drow = i * 16 + wv * 4 + (lane >> 4);                               \
        int offg = ((lane & 15) * 16) ^ ((drow & 7) << 5);                      \
        const char* g = in_b + (size_t)drow * 2048 + (kc_) * 256 + offg;        \
        gload_lds16(g, (char*)a_lds[buf] + i * 4096 + wv * 1024);               \
    }                                                                           \
    _Pragma("unroll")                                                           \
    for (int i = 0; i < 2; ++i) {       /* B: 8 KB */                           \
        int drow = i * 32 + wv * 8 + (lane >> 3);                               \
        int offg = ((lane & 7) * 16) ^ ((drow & 7) << 4);                       \
        const char* g = w_b + (size_t)drow * 1024 + (kc_) * 128 + offg;         \
        gload_lds16(g, (char*)b_lds[buf] + i * 4096 + wv * 1024);               \
    }                                                                           \
} while (0)

    PSTAGE(0, 0);
    asm volatile("s_waitcnt vmcnt(0)" ::: "memory");
    __builtin_amdgcn_s_barrier();
    asm volatile("" ::: "memory");

    f32x4 acc[4] = {};
    int row_a = wv * 16 + lrow;
    int abase = row_a * 256;
    int axor = (row_a & 7) << 5;
    int cur = 0;

#pragma unroll
    for (int kc = 0; kc < 8; ++kc) {
        if (kc < 7) {
            PSTAGE(cur ^ 1, kc + 1);                         // prefetch next chunk
            asm volatile("s_waitcnt vmcnt(6)" ::: "memory"); // current chunk landed
        } else {
            asm volatile("s_waitcnt vmcnt(0)" ::: "memory");
        }
        __builtin_amdgcn_s_barrier();
        asm volatile("" ::: "memory");

        const char* abuf = (const char*)a_lds[cur];
        const char* bbuf = (const char*)b_lds[cur];
#pragma unroll
        for (int kk = 0; kk < 2; ++kk) {
            int aoff = abase + ((kk * 128 + lkhi * 32) ^ axor);
            float4 x0 = *reinterpret_cast<const float4*>(abuf + aoff);
            float4 x1 = *reinterpret_cast<const float4*>(abuf + aoff + 16);
            short8 af;
            unsigned* au = reinterpret_cast<unsigned*>(&af);
            au[0] = bf2pack(x0.x, x0.y);
            au[1] = bf2pack(x0.z, x0.w);
            au[2] = bf2pack(x1.x, x1.y);
            au[3] = bf2pack(x1.z, x1.w);
#pragma unroll
            for (int ct = 0; ct < 4; ++ct) {
                int row_b = ct * 16 + lrow;
                int boff = row_b * 128 + ((kk * 64 + lkhi * 16) ^ ((row_b & 7) << 4));
                short8 bf = *reinterpret_cast<const short8*>(bbuf + boff);
                acc[ct] = __builtin_amdgcn_mfma_f32_16x16x32_bf16(af, bf, acc[ct], 0, 0, 0);
            }
        }
        __builtin_amdgcn_s_barrier();   // readers done before buf is restaged
        asm volatile("" ::: "memory");
        cur ^= 1;
    }
#undef PSTAGE

    float scale = (p == 0) ? 0.18033688011112042f : 1.0f;  // 0.125*log2(e)
    for (int ct = 0; ct < 4; ++ct) {
        for (int r = 0; r < 4; ++r) {
            int row = m0w + lkhi * 4 + r;       // global flat s index
            int col = ct * 16 + lrow;           // output dim
            unsigned short val = f2bf(acc[ct][r] * scale);
            if (p == 0)       qb[(size_t)row * DOUT + col] = val;
            else if (p == 1)  kb[(size_t)row * DOUT + col] = val;
            else {
                int bb = row >> 12, ss = row & 4095;
                vtb[((size_t)bb * DOUT + col) * S_ + ss] = val;
            }
        }
    }
}

// ---------------------------------------------------------------------------
// Kernel 2a: split-KV causal flash attention, phase 1 (partials, bf16 Opart).
// Swapped QK^T: sc = mfma(K, Q) -> lane holds S[q=qloc][kv=ct*16+lkhi4+r].
// Row-softmax = in-lane trees + 2 shuffles. Log2 domain.
// ---------------------------------------------------------------------------
__global__ __launch_bounds__(256) void attn_part(
    const unsigned short* __restrict__ qb, const unsigned short* __restrict__ kb,
    const unsigned short* __restrict__ vtb, unsigned short* __restrict__ Opart,
    float* __restrict__ ml)
{
    __shared__ unsigned short k_lds[2][KVB * DOUT];   // 2 x 8 KB
    __shared__ unsigned short v_lds[2][DOUT * KVB];   // 2 x 8 KB
    __shared__ unsigned short p_lds[4][16 * KVB];     // 8 KB

    int b = blockIdx.y;
    int x = NCHUNK_TOT - 1 - blockIdx.x;   // longest-first dispatch order
    int m = 0;
    while (4 * (m + 1) * (m + 2) <= x) ++m;
    int rem = x - 4 * m * (m + 1);
    int j = rem / (m + 1), c = rem % (m + 1);
    int qt = 8 * m + j;

    int q0 = qt * QB;
    int tid = threadIdx.x, wv = tid >> 6, lane = tid & 63;
    int lrow = lane & 15, lkhi = lane >> 4;
    int lkhi4 = lkhi * 4;
    int qloc = wv * 16 + lrow;             // q-row (block-local) this lane reduces

    const unsigned short* Qbase = qb + ((size_t)b * S_ + q0 + wv * 16 + lrow) * DOUT;
    short8 qf[2];
    qf[0] = *reinterpret_cast<const short8*>(Qbase + lkhi * 8);
    qf[1] = *reinterpret_cast<const short8*>(Qbase + 32 + lkhi * 8);

    f32x4 o[4] = {};
    float m_run = -INFINITY, l_run = 0.f;   // stats for q = qloc (log2 domain)

    const unsigned short* Kg = kb + (size_t)b * S_ * DOUT;
    const unsigned short* Vg = vtb + (size_t)b * DOUT * S_;
    char* pw = reinterpret_cast<char*>(p_lds[wv]);

    int srow_lo = (lane >> 3);             // 0..7
    int schunk = (lane & 7) * 16;          // within-row byte
    int soff = schunk ^ (srow_lo << 4);    // inverse-swizzled source byte

    int kv_beg = c * 8;
    int kv_end = min(kv_beg + 8, qt + 1);
    int cur = 0;

#define STAGE(buf, kvt_) do {                                                  \
    int kv0_ = (kvt_) * KVB;                                                   \
    for (int h = 0; h < 2; ++h) {                                              \
        int r_ = wv * 16 + h * 8 + srow_lo;                                    \
        const char* gk_ = (const char*)(Kg + (size_t)(kv0_ + r_) * DOUT) + soff; \
        gload_lds16(gk_, (char*)k_lds[buf] + wv * 2048 + h * 1024);            \
        const char* gv_ = (const char*)(Vg + (size_t)r_ * S_ + kv0_) + soff;   \
        gload_lds16(gv_, (char*)v_lds[buf] + wv * 2048 + h * 1024);            \
    }                                                                          \
} while (0)

    STAGE(0, kv_beg);
    asm volatile("s_waitcnt vmcnt(0)" ::: "memory");
    __builtin_amdgcn_s_barrier();
    asm volatile("" ::: "memory");

    for (int kvt = kv_beg; kvt < kv_end; ++kvt) {
        if (kvt + 1 < kv_end) STAGE(cur ^ 1, kvt + 1);  // prefetch under compute

        const char* kl = (const char*)k_lds[cur];
        const char* vl = (const char*)v_lds[cur];

        // swapped QK^T: sc[ct][r] = S[q=qloc][kv = ct*16+lkhi4+r]
        f32x4 sc[4];
        __builtin_amdgcn_s_setprio(1);
        for (int ct = 0; ct < 4; ++ct) {
            f32x4 a = {};
            for (int ds = 0; ds < 2; ++ds) {
                int r = ct * 16 + lrow;
                int byte = (r * 128 + (ds * 32 + lkhi * 8) * 2) ^ ((r & 7) << 4);
                short8 kf = *reinterpret_cast<const short8*>(kl + byte);
                a = __builtin_amdgcn_mfma_f32_16x16x32_bf16(kf, qf[ds], a, 0, 0, 0);
            }
            sc[ct] = a;
        }
        __builtin_amdgcn_s_setprio(0);

        // causal mask (diag tile only): kv_local > q_local (incl. wave offset!)
        if (kvt == qt) {
            for (int ct = 0; ct < 4; ++ct)
                for (int r = 0; r < 4; ++r)
                    if (ct * 16 + lkhi4 + r > qloc) sc[ct][r] = -INFINITY;
        }

        // row max: in-lane tree + xor16/xor32
        float mx4[4];
        for (int ct = 0; ct < 4; ++ct)
            mx4[ct] = fmaxf(fmaxf(sc[ct][0], sc[ct][1]), fmaxf(sc[ct][2], sc[ct][3]));
        float mxl = fmaxf(fmaxf(mx4[0], mx4[1]), fmaxf(mx4[2], mx4[3]));
        mxl = fmaxf(mxl, __shfl_xor(mxl, 16));
        mxl = fmaxf(mxl, __shfl_xor(mxl, 32));
        float mnew = fmaxf(m_run, mxl);
        float corr = fast_exp2(m_run - mnew);

        // P = exp2(S - mnew); row sum
        float s4[4];
        for (int ct = 0; ct < 4; ++ct) {
            sc[ct][0] = fast_exp2(sc[ct][0] - mnew);
            sc[ct][1] = fast_exp2(sc[ct][1] - mnew);
            sc[ct][2] = fast_exp2(sc[ct][2] - mnew);
            sc[ct][3] = fast_exp2(sc[ct][3] - mnew);
            s4[ct] = (sc[ct][0] + sc[ct][1]) + (sc[ct][2] + sc[ct][3]);
        }
        float rs = (s4[0] + s4[1]) + (s4[2] + s4[3]);
        rs += __shfl_xor(rs, 16);
        rs += __shfl_xor(rs, 32);
        l_run = l_run * corr + rs;
        m_run = mnew;

        // rescale O (o[ct2][r] is row q=lkhi4+r; corr lives in lane lkhi4+r)
        float corrq[4];
        for (int r = 0; r < 4; ++r) corrq[r] = __shfl(corr, lkhi4 + r);
        for (int ct2 = 0; ct2 < 4; ++ct2)
            for (int r = 0; r < 4; ++r)
                o[ct2][r] *= corrq[r];

        // P -> per-wave LDS (A-layout source): row=q=lrow, col=kv, b64 packed
        for (int ct = 0; ct < 4; ++ct) {
            uint2 pk;
            pk.x = bf2pack(sc[ct][0], sc[ct][1]);
            pk.y = bf2pack(sc[ct][2], sc[ct][3]);
            int byte = (lrow * 128 + (ct * 16 + lkhi4) * 2) ^ ((lrow & 7) << 4);
            *reinterpret_cast<uint2*>(pw + byte) = pk;
        }

        // PV: A = P (rows=q), B = Vt (cols=d, k=kv contiguous)
        __builtin_amdgcn_s_setprio(1);
        for (int ct2 = 0; ct2 < 4; ++ct2) {
            for (int ks = 0; ks < 2; ++ks) {
                int pbyte = (lrow * 128 + (ks * 32 + lkhi * 8) * 2) ^ ((lrow & 7) << 4);
                short8 pf = *reinterpret_cast<const short8*>(pw + pbyte);
                int vr = ct2 * 16 + lrow;
                int vbyte = (vr * 128 + (ks * 32 + lkhi * 8) * 2) ^ ((vr & 7) << 4);
                short8 vf = *reinterpret_cast<const short8*>(vl + vbyte);
                o[ct2] = __builtin_amdgcn_mfma_f32_16x16x32_bf16(pf, vf, o[ct2], 0, 0, 0);
            }
        }
        __builtin_amdgcn_s_setprio(0);
        __syncthreads();   // drains the prefetch issued at loop top
        cur ^= 1;
    }
#undef STAGE

    // write partials (unnormalized O as bf16 + per-row m,l in log2 domain)
    unsigned short* Op = Opart + ((size_t)b * NCHUNK_TOT + x) * (64 * 64);
    float* Ml = ml + ((size_t)b * NCHUNK_TOT + x) * (64 * 2);
    for (int r = 0; r < 4; ++r) {
        int qr = wv * 16 + lkhi4 + r;
        for (int ct2 = 0; ct2 < 4; ++ct2)
            Op[qr * 64 + ct2 * 16 + lrow] = f2bf(o[ct2][r]);
    }
    if (lkhi == 0) {
        int qr = wv * 16 + lrow;
        Ml[qr * 2 + 0] = m_run;
        Ml[qr * 2 + 1] = l_run;
    }
}

// ---------------------------------------------------------------------------
// Kernel 2b: combine bf16 partials (log2-domain m). grid (64, B), 256 thr.
// thread -> (row = tid>>2, 16-col group = (tid&3)*16)
// ---------------------------------------------------------------------------
__global__ __launch_bounds__(256) void attn_combine(
    const unsigned short* __restrict__ Opart, const float* __restrict__ ml,
    float* __restrict__ out)
{
    int qt = blockIdx.x, b = blockIdx.y;
    int m = qt >> 3;
    int nch = m + 1;
    int cbase = 4 * m * (m + 1) + (qt - 8 * m) * nch;

    int r = threadIdx.x >> 2;
    int cg = (threadIdx.x & 3) * 16;

    float M = -INFINITY;
    for (int c = 0; c < nch; ++c)
        M = fmaxf(M, ml[(((size_t)b * NCHUNK_TOT + cbase + c) * 64 + r) * 2]);

    float L = 0.f;
    float acc[16];
#pragma unroll
    for (int i = 0; i < 16; ++i) acc[i] = 0.f;

    for (int c = 0; c < nch; ++c) {
        size_t ci = (size_t)b * NCHUNK_TOT + cbase + c;
        float mc = ml[(ci * 64 + r) * 2 + 0];
        float lc = ml[(ci * 64 + r) * 2 + 1];
        float w = fast_exp2(mc - M);
        L += lc * w;
        const unsigned short* Op = Opart + ci * (64 * 64) + r * 64 + cg;
        short8 v0 = *reinterpret_cast<const short8*>(Op);
        short8 v1 = *reinterpret_cast<const short8*>(Op + 8);
#pragma unroll
        for (int i = 0; i < 8; ++i) {
            acc[i]     += bf2f((unsigned short)v0[i]) * w;
            acc[8 + i] += bf2f((unsigned short)v1[i]) * w;
        }
    }
    float inv = 1.f / L;
    float* dst = out + (((size_t)b * S_) + qt * 64 + r) * DOUT + cg;
#pragma unroll
    for (int i = 0; i < 4; ++i) {
        f32x4 v = { acc[4*i] * inv, acc[4*i+1] * inv, acc[4*i+2] * inv, acc[4*i+3] * inv };
        *reinterpret_cast<f32x4*>(dst + 4 * i) = v;
    }
}

extern "C" void kernel_launch(void* const* d_in, const int* in_sizes, int n_in,
                              void* d_out, int out_size, void* d_ws, size_t ws_size,
                              hipStream_t stream) {
    const float* key_in = (const float*)d_in[0];
    const float* val_in = (const float*)d_in[1];
    const float* qry_in = (const float*)d_in[2];
    const float* Wk = (const float*)d_in[3];
    const float* Wv = (const float*)d_in[4];
    const float* Wq = (const float*)d_in[5];
    float* out = (float*)d_out;

    char* ws = (char*)d_ws;
    size_t off = 0;
    unsigned short* qb  = (unsigned short*)(ws + off); off += (size_t)B_ * S_ * DOUT * 2;
    unsigned short* kb  = (unsigned short*)(ws + off); off += (size_t)B_ * S_ * DOUT * 2;
    unsigned short* vtb = (unsigned short*)(ws + off); off += (size_t)B_ * S_ * DOUT * 2;
    unsigned short* wt  = (unsigned short*)(ws + off); off += (size_t)3 * DIN * DOUT * 2;
    unsigned short* Opart = (unsigned short*)(ws + off); off += (size_t)B_ * NCHUNK_TOT * 64 * 64 * 2;
    float* ml    = (float*)(ws + off); off += (size_t)B_ * NCHUNK_TOT * 64 * 2 * 4;

    wt_kernel<<<dim3(8, 3), 256, 0, stream>>>(Wq, Wk, Wv, wt);
    proj_kernel<<<dim3(256, 3), 256, 0, stream>>>(qry_in, key_in, val_in, wt, qb, kb, vtb);
    attn_part<<<dim3(NCHUNK_TOT, B_), 256, 0, stream>>>(qb, kb, vtb, Opart, ml);
    attn_combine<<<dim3(S_ / QB, B_), 256, 0, stream>>>(Opart, ml, out);
}